// Round 11
// baseline (154.655 us; speedup 1.0000x reference)
//
#include <hip/hip_runtime.h>
#include <math.h>

typedef _Float16 half8 __attribute__((ext_vector_type(8)));
typedef _Float16 half4v __attribute__((ext_vector_type(4)));
typedef float floatx4 __attribute__((ext_vector_type(4)));

// ---------------------------------------------------------------------------
// Prep: hih = (f16)(E@W1a + b1) linear; hjF = (f16)(E@W1b) PRE-SWIZZLED into
// MFMA B-fragment order per 16-row j-tile:
//   hjF[((jt*4+ks)*64 + lq*16+lr)*8 + q] = hj[16*jt+lr][ks*32+lq*8+q]
// (fragment = 64 lanes x 16B, contiguous -> global_load_lds-compatible).
// blocks 0..1023: one (b,s) row. block 1024: W2frag. block 1025: W3frag.
// ---------------------------------------------------------------------------
__global__ __launch_bounds__(256) void prep_kernel(
    const float* __restrict__ E,
    const float* __restrict__ W1,
    const float* __restrict__ b1,
    const float* __restrict__ W2,
    const float* __restrict__ W3,
    _Float16* __restrict__ hih,
    _Float16* __restrict__ hjF,
    _Float16* __restrict__ W2frag,
    _Float16* __restrict__ W3frag)
{
    const int blk = blockIdx.x;
    const int t = threadIdx.x;
    if (blk < 1024) {
        __shared__ float sE[128];
        if (t < 128) sE[t] = E[blk*128 + t];
        __syncthreads();
        const int half = t >> 7;       // 0: hi (with b1), 1: hj
        const int k = t & 127;
        float acc = half ? 0.f : b1[k];
        const float* w1col = &W1[half*128*128 + k];
        #pragma unroll 8
        for (int d = 0; d < 128; ++d)
            acc = fmaf(sE[d], w1col[d*128], acc);
        if (half == 0) {
            hih[blk*128 + k] = (_Float16)acc;
        } else {
            const int jt = blk >> 4, lr = blk & 15;
            const int ks = k >> 5, lq = (k >> 3) & 3, q = k & 7;
            hjF[(((jt*4 + ks)*64) + lq*16 + lr)*8 + q] = (_Float16)acc;
        }
    } else if (blk == 1024) {
        // A-frag order: frag g=((wr*4+nt)*4+ks), lane l, elem q holds
        // W2t[n][k]=W2[k][n], n=64*wr+16*nt+(l&15), k=ks*32+(l>>4)*8+q
        for (int e = t; e < 16384; e += 256) {
            int q = e & 7, l = (e >> 3) & 63, g = e >> 9;
            int wr = g >> 4, nt = (g >> 2) & 3, ks = g & 3;
            int row = 64*wr + 16*nt + (l & 15);
            int k = ks*32 + (l >> 4)*8 + q;
            W2frag[e] = (_Float16)W2[k*128 + row];
        }
    } else {
        // B-frag order: frag ks, lane l, elem q holds W3[k][n2],
        // n2=l&15, k=ks*32+(l>>4)*8+q
        for (int e = t; e < 2048; e += 256) {
            int q = e & 7, l = (e >> 3) & 63, ks = e >> 9;
            int k = ks*32 + (l >> 4)*8 + q;
            W3frag[e] = (_Float16)W3[k*16 + (l & 15)];
        }
    }
}

// ---------------------------------------------------------------------------
// Main: one block = (b, i, j0..j0+127). Bulk ASYNC staging of the block's 32
// pre-swizzled hj B-fragments (global_load_lds width=16, wave-uniform base +
// lane*16 — the exact required shape). GEMM1' from LDS (conflict-free
// lane*16 reads), H2 written back in GEMM2 A-fragment order (conflict-free),
// GEMM2, f32 output. LDS = 32KB -> 4 blocks/CU.
// ---------------------------------------------------------------------------
__global__ __launch_bounds__(256, 4) void main_kernel(
    const _Float16* __restrict__ hih,
    const _Float16* __restrict__ hjF,
    const _Float16* __restrict__ W2frag,
    const _Float16* __restrict__ W3frag,
    const float* __restrict__ b2,
    const float* __restrict__ b3,
    const float* __restrict__ temps,
    const int* __restrict__ mask,
    float* __restrict__ out)
{
    __shared__ _Float16 sB[16384];   // 32KB: hj B-frags, then H2 A-frags

    const int tid = threadIdx.x;
    const int bid = blockIdx.x;
    const int b  = bid >> 11;
    const int i  = (bid >> 2) & 511;
    const int j0 = (bid & 3) << 7;

    const int lane = tid & 63;
    const int wave = tid >> 6;
    const int wr = wave >> 1;   // n-strip (64)
    const int wc = wave & 1;    // m-strip (64)
    const int lr = lane & 15;
    const int lq = lane >> 4;

    // ---- Fire async staging FIRST: 32 frags x 1KB, 8 per wave ----
    const _Float16* gsrc = hjF + (size_t)((b*32 + (bid & 3)*8)*4) * 512;
    #pragma unroll
    for (int f8 = 0; f8 < 8; ++f8) {
        const int f = wave*8 + f8;
        const _Float16* src = gsrc + f*512 + lane*8;
        _Float16* dst = &sB[f*512];
#if __has_builtin(__builtin_amdgcn_global_load_lds)
        __builtin_amdgcn_global_load_lds(
            (const __attribute__((address_space(1))) void*)src,
            (__attribute__((address_space(3))) void*)dst, 16, 0, 0);
#else
        *(half8*)(dst + lane*8) = *(const half8*)src;
#endif
    }

    // ---- Overlap with register preloads (independent of staging) ----
    const half8 zero8 = {};
    const _Float16* hirow = &hih[(b*512 + i)*128];
    const half8* w2v = (const half8*)W2frag;
    const half8* w3v = (const half8*)W3frag;

    half8 aW[4][4];
    #pragma unroll
    for (int nt = 0; nt < 4; ++nt)
        #pragma unroll
        for (int ks = 0; ks < 4; ++ks)
            aW[nt][ks] = w2v[((wr*4 + nt)*4 + ks)*64 + lane];

    half8 hiF[4];
    #pragma unroll
    for (int ks = 0; ks < 4; ++ks)
        hiF[ks] = *(const half8*)&hirow[ks*32 + lq*8];

    const int* mrow = &mask[(b*512 + i)*512];
    const int m0e = 32*wave;             // GEMM2/epilogue strip
    const int4 mk0 = *(const int4*)&mrow[j0 + m0e + 4*lq];
    const int4 mk1 = *(const int4*)&mrow[j0 + m0e + 16 + 4*lq];

    __syncthreads();   // drains staging (vmcnt) + joins waves

    // GEMM1': D[n][m] = sum_k W2[k][n] * relu(hi[k]+hj[m][k])
    floatx4 acc[4][4] = {};
    #pragma unroll
    for (int ks = 0; ks < 4; ++ks) {
        half8 bF[4];
        #pragma unroll
        for (int mt = 0; mt < 4; ++mt) {
            half8 hj8 = *(const half8*)&sB[((4*wc + mt)*4 + ks)*512 + lane*8];
            bF[mt] = __builtin_elementwise_max(hiF[ks] + hj8, zero8);
        }
        #pragma unroll
        for (int nt = 0; nt < 4; ++nt)
            #pragma unroll
            for (int mt = 0; mt < 4; ++mt)
                acc[nt][mt] = __builtin_amdgcn_mfma_f32_16x16x32_f16(
                    aW[nt][ks], bF[mt], acc[nt][mt], 0, 0, 0);
    }
    __syncthreads();   // all waves done reading hj frags

    // H2[m][n] = relu(D + b2[n]) written in GEMM2 A-frag order:
    //   frag = s*8 + sub*4 + ks2, s=2wc+(mt>>1), sub=mt&1, ks2=2wr+(nt>>1)
    //   lane l2 = lr + 16*(2*(nt&1)+(lq>>1)), halves q2 = 4*(lq&1)+r
    #pragma unroll
    for (int nt = 0; nt < 4; ++nt) {
        const int nb = 64*wr + 16*nt + 4*lq;
        const float4 bv = *(const float4*)&b2[nb];
        const int ks2 = 2*wr + (nt >> 1);
        const int l2 = lr + 16*(2*(nt & 1) + (lq >> 1));
        #pragma unroll
        for (int mt = 0; mt < 4; ++mt) {
            const int frag = (2*wc + (mt >> 1))*8 + (mt & 1)*4 + ks2;
            floatx4 v = acc[nt][mt];
            half4v o;
            o[0] = (_Float16)fmaxf(v[0] + bv.x, 0.f);
            o[1] = (_Float16)fmaxf(v[1] + bv.y, 0.f);
            o[2] = (_Float16)fmaxf(v[2] + bv.z, 0.f);
            o[3] = (_Float16)fmaxf(v[3] + bv.w, 0.f);
            *(half4v*)&sB[frag*512 + l2*8 + 4*(lq & 1)] = o;
        }
    }
    __syncthreads();   // H2 frags complete before cross-wave reads

    // GEMM2: D2[m][n2] = sum_n H2[m][n] * W3[n][n2]; strip = wave
    floatx4 acc2[2] = {};
    #pragma unroll
    for (int ks = 0; ks < 4; ++ks) {
        half8 bW = w3v[ks*64 + lane];
        half8 a0 = *(const half8*)&sB[(wave*8 + ks)*512 + lane*8];
        half8 a1 = *(const half8*)&sB[(wave*8 + 4 + ks)*512 + lane*8];
        acc2[0] = __builtin_amdgcn_mfma_f32_16x16x32_f16(a0, bW, acc2[0], 0, 0, 0);
        acc2[1] = __builtin_amdgcn_mfma_f32_16x16x32_f16(a1, bW, acc2[1], 0, 0, 0);
    }

    // Epilogue: bias = (comp + b3)*temp, mask -> -inf, float4 stores (f32 out)
    const int n2 = lr;
    const float tempv = temps[n2];
    const float b3v = b3[n2];
    float* outp = &out[(((b*16 + n2)*512) + i)*512];
    {
        const int j = j0 + m0e + 4*lq;
        floatx4 v = acc2[0];
        float4 res;
        res.x = mk0.x ? (v[0] + b3v)*tempv : -INFINITY;
        res.y = mk0.y ? (v[1] + b3v)*tempv : -INFINITY;
        res.z = mk0.z ? (v[2] + b3v)*tempv : -INFINITY;
        res.w = mk0.w ? (v[3] + b3v)*tempv : -INFINITY;
        *(float4*)&outp[j] = res;
    }
    {
        const int j = j0 + m0e + 16 + 4*lq;
        floatx4 v = acc2[1];
        float4 res;
        res.x = mk1.x ? (v[0] + b3v)*tempv : -INFINITY;
        res.y = mk1.y ? (v[1] + b3v)*tempv : -INFINITY;
        res.z = mk1.z ? (v[2] + b3v)*tempv : -INFINITY;
        res.w = mk1.w ? (v[3] + b3v)*tempv : -INFINITY;
        *(float4*)&outp[j] = res;
    }
}

extern "C" void kernel_launch(void* const* d_in, const int* in_sizes, int n_in,
                              void* d_out, int out_size, void* d_ws, size_t ws_size,
                              hipStream_t stream)
{
    const float* E     = (const float*)d_in[0];
    const int* mask    = (const int*)d_in[1];
    const float* W1    = (const float*)d_in[2];
    const float* b1    = (const float*)d_in[3];
    const float* W2    = (const float*)d_in[4];
    const float* b2    = (const float*)d_in[5];
    const float* W3    = (const float*)d_in[6];
    const float* b3    = (const float*)d_in[7];
    const float* temps = (const float*)d_in[8];

    char* ws = (char*)d_ws;
    _Float16* hih = (_Float16*)ws;                       // 1024*128 f16 = 256KB
    _Float16* hjF = (_Float16*)(ws + 262144);            // 256KB (swizzled)
    _Float16* W2f = (_Float16*)(ws + 524288);            // 32KB
    _Float16* W3f = W2f + 16384;                         // 4KB

    prep_kernel<<<1026, 256, 0, stream>>>(E, W1, b1, W2, W3, hih, hjF, W2f, W3f);
    main_kernel<<<4096, 256, 0, stream>>>(hih, hjF, W2f, W3f, b2, b3, temps, mask,
                                          (float*)d_out);
}

// Round 12
// 152.729 us; speedup vs baseline: 1.0126x; 1.0126x over previous
//
#include <hip/hip_runtime.h>
#include <math.h>

typedef _Float16 half8 __attribute__((ext_vector_type(8)));
typedef _Float16 half4v __attribute__((ext_vector_type(4)));
typedef float floatx4 __attribute__((ext_vector_type(4)));

// ---------------------------------------------------------------------------
// Prep: hih = (f16)(E@W1a + b1) linear; hjF = (f16)(E@W1b) PRE-SWIZZLED into
// MFMA B-fragment order per 16-row j-tile:
//   hjF[((jt*4+ks)*64 + lq*16+lr)*8 + q] = hj[16*jt+lr][ks*32+lq*8+q]
// (fragment = 64 lanes x 16B contiguous -> staging is one b128/lane).
// blocks 0..1023: one (b,s) row. block 1024: W2frag. block 1025: W3frag.
// ---------------------------------------------------------------------------
__global__ __launch_bounds__(256) void prep_kernel(
    const float* __restrict__ E,
    const float* __restrict__ W1,
    const float* __restrict__ b1,
    const float* __restrict__ W2,
    const float* __restrict__ W3,
    _Float16* __restrict__ hih,
    _Float16* __restrict__ hjF,
    _Float16* __restrict__ W2frag,
    _Float16* __restrict__ W3frag)
{
    const int blk = blockIdx.x;
    const int t = threadIdx.x;
    if (blk < 1024) {
        __shared__ float sE[128];
        if (t < 128) sE[t] = E[blk*128 + t];
        __syncthreads();
        const int half = t >> 7;       // 0: hi (with b1), 1: hj
        const int k = t & 127;
        float acc = half ? 0.f : b1[k];
        const float* w1col = &W1[half*128*128 + k];
        #pragma unroll 8
        for (int d = 0; d < 128; ++d)
            acc = fmaf(sE[d], w1col[d*128], acc);
        if (half == 0) {
            hih[blk*128 + k] = (_Float16)acc;
        } else {
            const int jt = blk >> 4, lr = blk & 15;
            const int ks = k >> 5, lq = (k >> 3) & 3, q = k & 7;
            hjF[(((jt*4 + ks)*64) + lq*16 + lr)*8 + q] = (_Float16)acc;
        }
    } else if (blk == 1024) {
        // A-frag order: frag g=((wr*4+nt)*4+ks), lane l, elem q holds
        // W2t[n][k]=W2[k][n], n=64*wr+16*nt+(l&15), k=ks*32+(l>>4)*8+q
        for (int e = t; e < 16384; e += 256) {
            int q = e & 7, l = (e >> 3) & 63, g = e >> 9;
            int wr = g >> 4, nt = (g >> 2) & 3, ks = g & 3;
            int row = 64*wr + 16*nt + (l & 15);
            int k = ks*32 + (l >> 4)*8 + q;
            W2frag[e] = (_Float16)W2[k*128 + row];
        }
    } else {
        // B-frag order: frag ks, lane l, elem q holds W3[k][n2],
        // n2=l&15, k=ks*32+(l>>4)*8+q
        for (int e = t; e < 2048; e += 256) {
            int q = e & 7, l = (e >> 3) & 63, ks = e >> 9;
            int k = ks*32 + (l >> 4)*8 + q;
            W3frag[e] = (_Float16)W3[k*16 + (l & 15)];
        }
    }
}

// ---------------------------------------------------------------------------
// Main: one block = (b, i, j0..j0+127). EXPLICIT bulk staging of the block's
// 32 pre-swizzled hj B-fragments: 8 independent global b128 loads/lane fired
// up-front (single vmcnt drain), then 8 conflict-free ds_write_b128. GEMM1'
// from LDS (lane*16 reads), H2 written back in GEMM2 A-fragment order
// (conflict-free), GEMM2, f32 output. LDS = 32KB -> 4 blocks/CU.
// NOTE: __builtin_amdgcn_global_load_lds was tried (R11) and lowered to a
// scratch round-trip (+128MB HBM writes) — do NOT reintroduce.
// ---------------------------------------------------------------------------
__global__ __launch_bounds__(256, 4) void main_kernel(
    const _Float16* __restrict__ hih,
    const _Float16* __restrict__ hjF,
    const _Float16* __restrict__ W2frag,
    const _Float16* __restrict__ W3frag,
    const float* __restrict__ b2,
    const float* __restrict__ b3,
    const float* __restrict__ temps,
    const int* __restrict__ mask,
    float* __restrict__ out)
{
    __shared__ _Float16 sB[16384];   // 32KB: hj B-frags, then H2 A-frags

    const int tid = threadIdx.x;
    const int bid = blockIdx.x;
    const int b  = bid >> 11;
    const int i  = (bid >> 2) & 511;
    const int j0 = (bid & 3) << 7;

    const int lane = tid & 63;
    const int wave = tid >> 6;
    const int wr = wave >> 1;   // n-strip (64)
    const int wc = wave & 1;    // m-strip (64)
    const int lr = lane & 15;
    const int lq = lane >> 4;

    // ---- Fire all staging loads FIRST (8 independent b128 per lane) ----
    const _Float16* gsrc = hjF + (size_t)((b*32 + (bid & 3)*8)*4) * 512;
    half8 stg[8];
    #pragma unroll
    for (int f8 = 0; f8 < 8; ++f8)
        stg[f8] = *(const half8*)(gsrc + (wave*8 + f8)*512 + lane*8);

    // ---- Overlap: register preloads independent of staging ----
    const half8 zero8 = {};
    const _Float16* hirow = &hih[(b*512 + i)*128];
    const half8* w2v = (const half8*)W2frag;
    const half8* w3v = (const half8*)W3frag;

    half8 aW[4][4];
    #pragma unroll
    for (int nt = 0; nt < 4; ++nt)
        #pragma unroll
        for (int ks = 0; ks < 4; ++ks)
            aW[nt][ks] = w2v[((wr*4 + nt)*4 + ks)*64 + lane];

    half8 hiF[4];
    #pragma unroll
    for (int ks = 0; ks < 4; ++ks)
        hiF[ks] = *(const half8*)&hirow[ks*32 + lq*8];

    const int* mrow = &mask[(b*512 + i)*512];
    const int m0e = 32*wave;             // GEMM2/epilogue strip
    const int4 mk0 = *(const int4*)&mrow[j0 + m0e + 4*lq];
    const int4 mk1 = *(const int4*)&mrow[j0 + m0e + 16 + 4*lq];

    // ---- Write staged fragments to LDS (conflict-free b128) ----
    #pragma unroll
    for (int f8 = 0; f8 < 8; ++f8)
        *(half8*)&sB[(wave*8 + f8)*512 + lane*8] = stg[f8];
    __syncthreads();

    // GEMM1': D[n][m] = sum_k W2[k][n] * relu(hi[k]+hj[m][k])
    floatx4 acc[4][4] = {};
    #pragma unroll
    for (int ks = 0; ks < 4; ++ks) {
        half8 bF[4];
        #pragma unroll
        for (int mt = 0; mt < 4; ++mt) {
            half8 hj8 = *(const half8*)&sB[((4*wc + mt)*4 + ks)*512 + lane*8];
            bF[mt] = __builtin_elementwise_max(hiF[ks] + hj8, zero8);
        }
        #pragma unroll
        for (int nt = 0; nt < 4; ++nt)
            #pragma unroll
            for (int mt = 0; mt < 4; ++mt)
                acc[nt][mt] = __builtin_amdgcn_mfma_f32_16x16x32_f16(
                    aW[nt][ks], bF[mt], acc[nt][mt], 0, 0, 0);
    }
    __syncthreads();   // all waves done reading hj frags

    // H2[m][n] = relu(D + b2[n]) written in GEMM2 A-frag order:
    //   frag = (2wc+(mt>>1))*8 + (mt&1)*4 + 2wr+(nt>>1)
    //   lane l2 = lr + 16*(2*(nt&1)+(lq>>1)), half-sel q2 = 4*(lq&1)
    #pragma unroll
    for (int nt = 0; nt < 4; ++nt) {
        const int nb = 64*wr + 16*nt + 4*lq;
        const float4 bv = *(const float4*)&b2[nb];
        const int ks2 = 2*wr + (nt >> 1);
        const int l2 = lr + 16*(2*(nt & 1) + (lq >> 1));
        #pragma unroll
        for (int mt = 0; mt < 4; ++mt) {
            const int frag = (2*wc + (mt >> 1))*8 + (mt & 1)*4 + ks2;
            floatx4 v = acc[nt][mt];
            half4v o;
            o[0] = (_Float16)fmaxf(v[0] + bv.x, 0.f);
            o[1] = (_Float16)fmaxf(v[1] + bv.y, 0.f);
            o[2] = (_Float16)fmaxf(v[2] + bv.z, 0.f);
            o[3] = (_Float16)fmaxf(v[3] + bv.w, 0.f);
            *(half4v*)&sB[frag*512 + l2*8 + 4*(lq & 1)] = o;
        }
    }
    __syncthreads();   // H2 frags complete before cross-wave reads

    // GEMM2: D2[m][n2] = sum_n H2[m][n] * W3[n][n2]; strip = wave
    floatx4 acc2[2] = {};
    #pragma unroll
    for (int ks = 0; ks < 4; ++ks) {
        half8 bW = w3v[ks*64 + lane];
        half8 a0 = *(const half8*)&sB[(wave*8 + ks)*512 + lane*8];
        half8 a1 = *(const half8*)&sB[(wave*8 + 4 + ks)*512 + lane*8];
        acc2[0] = __builtin_amdgcn_mfma_f32_16x16x32_f16(a0, bW, acc2[0], 0, 0, 0);
        acc2[1] = __builtin_amdgcn_mfma_f32_16x16x32_f16(a1, bW, acc2[1], 0, 0, 0);
    }

    // Epilogue: bias = (comp + b3)*temp, mask -> -inf, float4 stores (f32 out)
    const int n2 = lr;
    const float tempv = temps[n2];
    const float b3v = b3[n2];
    float* outp = &out[(((b*16 + n2)*512) + i)*512];
    {
        const int j = j0 + m0e + 4*lq;
        floatx4 v = acc2[0];
        float4 res;
        res.x = mk0.x ? (v[0] + b3v)*tempv : -INFINITY;
        res.y = mk0.y ? (v[1] + b3v)*tempv : -INFINITY;
        res.z = mk0.z ? (v[2] + b3v)*tempv : -INFINITY;
        res.w = mk0.w ? (v[3] + b3v)*tempv : -INFINITY;
        *(float4*)&outp[j] = res;
    }
    {
        const int j = j0 + m0e + 16 + 4*lq;
        floatx4 v = acc2[1];
        float4 res;
        res.x = mk1.x ? (v[0] + b3v)*tempv : -INFINITY;
        res.y = mk1.y ? (v[1] + b3v)*tempv : -INFINITY;
        res.z = mk1.z ? (v[2] + b3v)*tempv : -INFINITY;
        res.w = mk1.w ? (v[3] + b3v)*tempv : -INFINITY;
        *(float4*)&outp[j] = res;
    }
}

extern "C" void kernel_launch(void* const* d_in, const int* in_sizes, int n_in,
                              void* d_out, int out_size, void* d_ws, size_t ws_size,
                              hipStream_t stream)
{
    const float* E     = (const float*)d_in[0];
    const int* mask    = (const int*)d_in[1];
    const float* W1    = (const float*)d_in[2];
    const float* b1    = (const float*)d_in[3];
    const float* W2    = (const float*)d_in[4];
    const float* b2    = (const float*)d_in[5];
    const float* W3    = (const float*)d_in[6];
    const float* b3    = (const float*)d_in[7];
    const float* temps = (const float*)d_in[8];

    char* ws = (char*)d_ws;
    _Float16* hih = (_Float16*)ws;                       // 1024*128 f16 = 256KB
    _Float16* hjF = (_Float16*)(ws + 262144);            // 256KB (swizzled)
    _Float16* W2f = (_Float16*)(ws + 524288);            // 32KB
    _Float16* W3f = W2f + 16384;                         // 4KB

    prep_kernel<<<1026, 256, 0, stream>>>(E, W1, b1, W2, W3, hih, hjF, W2f, W3f);
    main_kernel<<<4096, 256, 0, stream>>>(hih, hjF, W2f, W3f, b2, b3, temps, mask,
                                          (float*)d_out);
}